// Round 5
// baseline (1298.738 us; speedup 1.0000x reference)
//
#include <hip/hip_runtime.h>

#define DEV_INLINE __device__ __forceinline__

// Problem dims (fixed by setup_inputs)
constexpr int B = 16, T = 4096, C = 512, K = 3;
constexpr int NC = 128;           // chunks along T
constexpr int L  = T / NC;        // 32 steps per chunk (out_local fits registers)
constexpr int C4 = C / 4;         // 128 float4 lanes across channels
constexpr int NBLK = B * NC;      // 2048 blocks
constexpr float EPS = 1e-4f;

// Single-pass decoupled-lookback scan (rocPRIM pattern):
//   x is read ONCE from HBM, out is written ONCE. No second sweep.
//   Each block: local zero-init pass (out_local in regs) -> publish local
//   suffix state (flag=LOCAL) -> lookback over predecessors (early-terminate
//   at flag=INCL) -> publish own inclusive state (flag=INCL) -> apply
//   correction out[j] = out_local[j] + sum_k m_k a_k^(j+1) E_k  (R2-verified math).
// Deadlock-free: ticket counter assigns virtual block ids in scheduling order,
// so resident blocks always hold the lowest unprocessed chunks. Visibility via
// agent-scope release/acquire atomics (cross-XCD safe, G16).
//
// ws layout (floats):
//   [0]              ticket counter (uint)
//   [16 .. 16+NBLK)  flags: 0 = not ready, 1 = LOCAL, 2 = INCL
//   [S_OFF ..)       local suffix states  s[vb][k][c]   (12.6 MB)
//   [I_OFF ..)       inclusive states     incl[vb][k][c] (12.6 MB)
constexpr size_t HDR_FLOATS = 4096;                      // 16 KB header (memset to 0)
constexpr size_t S_OFF = HDR_FLOATS;
constexpr size_t I_OFF = S_OFF + (size_t)NBLK * K * C;

typedef float f4v __attribute__((ext_vector_type(4)));

DEV_INLINE float4 f4mul(float4 a, float4 b) {
  return make_float4(a.x * b.x, a.y * b.y, a.z * b.z, a.w * b.w);
}
DEV_INLINE float4 f4add(float4 a, float4 b) {
  return make_float4(a.x + b.x, a.y + b.y, a.z + b.z, a.w + b.w);
}
DEV_INLINE float4 f4fma(float4 a, float4 b, float4 c) {
  return make_float4(fmaf(a.x, b.x, c.x), fmaf(a.y, b.y, c.y),
                     fmaf(a.z, b.z, c.z), fmaf(a.w, b.w, c.w));
}
DEV_INLINE float4 f4onesub(float4 a) {
  return make_float4(1.f - a.x, 1.f - a.y, 1.f - a.z, 1.f - a.w);
}

DEV_INLINE float sig_clamp(float v) {
  float a = 1.0f / (1.0f + __expf(-v));
  return fminf(fmaxf(a, EPS), 1.0f - EPS);
}
DEV_INLINE float4 sig4(float4 v) {
  return make_float4(sig_clamp(v.x), sig_clamp(v.y), sig_clamp(v.z), sig_clamp(v.w));
}

DEV_INLINE void sm3(float l0, float l1, float l2, float& o0, float& o1, float& o2) {
  float mx = fmaxf(l0, fmaxf(l1, l2));
  float e0 = __expf(l0 - mx), e1 = __expf(l1 - mx), e2 = __expf(l2 - mx);
  float inv = 1.0f / (e0 + e1 + e2);
  o0 = e0 * inv; o1 = e1 * inv; o2 = e2 * inv;
}

// x is read exactly once -> nontemporal load (no L3 allocate; L3 stays free
// for carry/flag traffic). out is write-once streaming -> nontemporal store.
DEV_INLINE float4 nt_load(const float4* p) {
  f4v t = __builtin_nontemporal_load(reinterpret_cast<const f4v*>(p));
  float4 r; r.x = t.x; r.y = t.y; r.z = t.z; r.w = t.w; return r;
}
DEV_INLINE void nt_store(float4* p, float4 v) {
  f4v t; t.x = v.x; t.y = v.y; t.z = v.z; t.w = v.w;
  __builtin_nontemporal_store(t, reinterpret_cast<f4v*>(p));
}

__global__ __launch_bounds__(128, 2) void ema_lookback(
    const float* __restrict__ x,
    const float* __restrict__ logit_alpha,
    const float* __restrict__ mix_logits,
    float* __restrict__ ws,
    float* __restrict__ out) {
  __shared__ unsigned s_vb;
  unsigned* hdr = (unsigned*)ws;
  if (threadIdx.x == 0) {
    s_vb = __hip_atomic_fetch_add(hdr, 1u, __ATOMIC_RELAXED, __HIP_MEMORY_SCOPE_AGENT);
  }
  __syncthreads();
  const int vb = (int)s_vb;            // virtual block id: b*NC + i, in scheduling order
  const int i  = vb & (NC - 1);
  const int c4 = threadIdx.x;
  unsigned* flags = hdr + 16;

  // per-channel tables
  const float4* la = (const float4*)logit_alpha;
  const float4 a0 = sig4(la[0 * C4 + c4]);
  const float4 a1 = sig4(la[1 * C4 + c4]);
  const float4 a2 = sig4(la[2 * C4 + c4]);
  const float4 b0 = f4onesub(a0), b1 = f4onesub(a1), b2 = f4onesub(a2);

  const float4* ml = (const float4*)mix_logits;   // [C][K] flattened
  const float4 q0 = ml[3 * c4 + 0];
  const float4 q1 = ml[3 * c4 + 1];
  const float4 q2 = ml[3 * c4 + 2];
  float4 m0, m1, m2;
  sm3(q0.x, q0.y, q0.z, m0.x, m1.x, m2.x);
  sm3(q0.w, q1.x, q1.y, m0.y, m1.y, m2.y);
  sm3(q1.z, q1.w, q2.x, m0.z, m1.z, m2.z);
  sm3(q2.y, q2.z, q2.w, m0.w, m1.w, m2.w);

  const float4* xb = (const float4*)x + (size_t)vb * L * C4 + c4;
  float4*       ob = (float4*)out     + (size_t)vb * L * C4 + c4;
  float4* sl = (float4*)(ws + S_OFF) + (size_t)vb * K * C4 + c4;
  float4* il = (float4*)(ws + I_OFF) + (size_t)vb * K * C4 + c4;

  if (i == 0) {
    // chunk 0: exact x0-init; output is final, publish inclusive end state.
    float4 x0 = nt_load(&xb[0]);
    float4 y0 = x0, y1 = x0, y2 = x0;
    nt_store(&ob[0], f4fma(m0, y0, f4fma(m1, y1, f4mul(m2, y2))));
    #pragma unroll
    for (int j = 1; j < L; ++j) {
      float4 xv = nt_load(&xb[(size_t)j * C4]);
      y0 = f4fma(a0, y0, f4mul(b0, xv));
      y1 = f4fma(a1, y1, f4mul(b1, xv));
      y2 = f4fma(a2, y2, f4mul(b2, xv));
      nt_store(&ob[(size_t)j * C4], f4fma(m0, y0, f4fma(m1, y1, f4mul(m2, y2))));
    }
    il[0 * C4] = y0; il[1 * C4] = y1; il[2 * C4] = y2;
    __syncthreads();
    if (threadIdx.x == 0) {
      __threadfence();
      __hip_atomic_store(&flags[vb], 2u, __ATOMIC_RELEASE, __HIP_MEMORY_SCOPE_AGENT);
    }
    return;
  }

  // ---- phase A: local zero-init pass; out_local kept in registers ----
  float4 y0 = make_float4(0.f, 0.f, 0.f, 0.f), y1 = y0, y2 = y0;
  float4 out_local[L];
  #pragma unroll
  for (int j = 0; j < L; ++j) {          // full unroll: static indices -> registers
    float4 xv = nt_load(&xb[(size_t)j * C4]);
    y0 = f4fma(a0, y0, f4mul(b0, xv));
    y1 = f4fma(a1, y1, f4mul(b1, xv));
    y2 = f4fma(a2, y2, f4mul(b2, xv));
    out_local[j] = f4fma(m0, y0, f4fma(m1, y1, f4mul(m2, y2)));
  }
  // publish local suffix state (flag = LOCAL)
  sl[0 * C4] = y0; sl[1 * C4] = y1; sl[2 * C4] = y2;
  __syncthreads();
  if (threadIdx.x == 0) {
    __threadfence();
    __hip_atomic_store(&flags[vb], 1u, __ATOMIC_RELEASE, __HIP_MEMORY_SCOPE_AGENT);
  }

  // A_L = a^L via 5 squarings (L = 32)
  float4 A0 = a0, A1 = a1, A2 = a2;
  #pragma unroll
  for (int s = 0; s < 5; ++s) { A0 = f4mul(A0, A0); A1 = f4mul(A1, A1); A2 = f4mul(A2, A2); }

  // ---- phase B: decoupled lookback for incoming state E = incl(i-1) ----
  // E = s_{i-1} + A_L s_{i-2} + ... + A_L^d incl(j)  (terminate at first INCL;
  // chunk 0 always publishes INCL, so termination is guaranteed)
  float4 P0 = make_float4(1.f, 1.f, 1.f, 1.f), P1 = P0, P2 = P0;
  float4 E0 = make_float4(0.f, 0.f, 0.f, 0.f), E1 = E0, E2 = E0;
  const float4* sbase = (const float4*)(ws + S_OFF);
  const float4* ibase = (const float4*)(ws + I_OFF);
  const int fb = vb - i;                 // flag index base for this batch row
  int j = i - 1;
  while (true) {
    unsigned f = __hip_atomic_load(&flags[fb + j], __ATOMIC_ACQUIRE, __HIP_MEMORY_SCOPE_AGENT);
    while (f == 0u) {
      __builtin_amdgcn_s_sleep(1);
      f = __hip_atomic_load(&flags[fb + j], __ATOMIC_ACQUIRE, __HIP_MEMORY_SCOPE_AGENT);
    }
    const float4* src = (f == 2u ? ibase : sbase) + (size_t)(fb + j) * K * C4 + c4;
    float4 v0 = src[0 * C4], v1 = src[1 * C4], v2 = src[2 * C4];
    E0 = f4fma(P0, v0, E0);
    E1 = f4fma(P1, v1, E1);
    E2 = f4fma(P2, v2, E2);
    if (f == 2u) break;
    P0 = f4mul(P0, A0); P1 = f4mul(P1, A1); P2 = f4mul(P2, A2);
    --j;
  }

  // ---- publish own inclusive state: incl(i) = A_L * E + s_local ----
  il[0 * C4] = f4fma(A0, E0, y0);
  il[1 * C4] = f4fma(A1, E1, y1);
  il[2 * C4] = f4fma(A2, E2, y2);
  __syncthreads();
  if (threadIdx.x == 0) {
    __threadfence();
    __hip_atomic_store(&flags[vb], 2u, __ATOMIC_RELEASE, __HIP_MEMORY_SCOPE_AGENT);
  }

  // ---- phase C: correction + streamed output ----
  // out[j] = out_local[j] + sum_k m_k a_k^(j+1) E_k   (R2-verified math)
  const float4 g0 = f4mul(m0, E0);
  const float4 g1 = f4mul(m1, E1);
  const float4 g2 = f4mul(m2, E2);
  float4 p0 = a0, p1 = a1, p2 = a2;
  #pragma unroll
  for (int j2 = 0; j2 < L; ++j2) {       // full unroll: static indices
    float4 corr = f4fma(p0, g0, f4fma(p1, g1, f4mul(p2, g2)));
    nt_store(&ob[(size_t)j2 * C4], f4add(out_local[j2], corr));
    p0 = f4mul(p0, a0); p1 = f4mul(p1, a1); p2 = f4mul(p2, a2);
  }
}

extern "C" void kernel_launch(void* const* d_in, const int* in_sizes, int n_in,
                              void* d_out, int out_size, void* d_ws, size_t ws_size,
                              hipStream_t stream) {
  const float* x           = (const float*)d_in[0];
  const float* logit_alpha = (const float*)d_in[1];
  const float* mix_logits  = (const float*)d_in[2];
  float* out = (float*)d_out;
  float* ws  = (float*)d_ws;

  // zero ticket + flags (16 KB); graph-capturable async memset
  hipMemsetAsync(ws, 0, HDR_FLOATS * sizeof(float), stream);
  ema_lookback<<<NBLK, 128, 0, stream>>>(x, logit_alpha, mix_logits, ws, out);
}

// Round 6
// 265.524 us; speedup vs baseline: 4.8912x; 4.8912x over previous
//
#include <hip/hip_runtime.h>

#define DEV_INLINE __device__ __forceinline__

// Problem dims (fixed by setup_inputs)
constexpr int B = 16, T = 4096, C = 512, K = 3;
constexpr int NC = 64;           // chunks along T
constexpr int L  = T / NC;       // 64 steps per chunk
constexpr int C4 = C / 4;        // 128 float4 lanes across channels
constexpr float EPS = 1e-4f;

// Measured-best structure (R1, 265.5 us total; ~75 us kernel slice over the
// ~190 us harness floor):
//   K1: per-chunk zero-init local suffix over x (normal loads -> x allocates
//       in the 256 MB Infinity Cache), writes chunk-end states (6.3 MB carry).
//   K2: re-derives chunk i's incoming state by scanning carries of chunks < i
//       (parallel redundant scan, L2/L3-served), re-runs the exact recurrence
//       over x (L3 hits) and writes out with NONTEMPORAL stores so the 134 MB
//       output stream does not evict x from L3 mid-kernel.
// HBM traffic = 134 MB x (K1) + 134 MB out (K2) = streaming minimum.
//
// Falsified alternatives (counter evidence in session journal):
//   R2 RMW correction: +WRITE (out written twice)         -> ~83 us slice
//   R3 grid.sync fusion: device fence + 2x WRITE          -> ~204 us slice
//   R4 NC=128: 4x carry-scan traffic, K2 FETCH ~128 MB    -> ~110 us slice
//   R5 decoupled lookback: out_local[32] spills at VGPR=128 cap -> scratch
//      round-trip ~400 MB, 1.1 ms                          -> dead end

typedef float f4v __attribute__((ext_vector_type(4)));

DEV_INLINE float4 f4mul(float4 a, float4 b) {
  return make_float4(a.x * b.x, a.y * b.y, a.z * b.z, a.w * b.w);
}
DEV_INLINE float4 f4fma(float4 a, float4 b, float4 c) {
  return make_float4(fmaf(a.x, b.x, c.x), fmaf(a.y, b.y, c.y),
                     fmaf(a.z, b.z, c.z), fmaf(a.w, b.w, c.w));
}
DEV_INLINE float4 f4onesub(float4 a) {
  return make_float4(1.f - a.x, 1.f - a.y, 1.f - a.z, 1.f - a.w);
}

DEV_INLINE float sig_clamp(float v) {
  float a = 1.0f / (1.0f + __expf(-v));
  return fminf(fmaxf(a, EPS), 1.0f - EPS);
}
DEV_INLINE float4 sig4(float4 v) {
  return make_float4(sig_clamp(v.x), sig_clamp(v.y), sig_clamp(v.z), sig_clamp(v.w));
}

DEV_INLINE void sm3(float l0, float l1, float l2, float& o0, float& o1, float& o2) {
  float mx = fmaxf(l0, fmaxf(l1, l2));
  float e0 = __expf(l0 - mx), e1 = __expf(l1 - mx), e2 = __expf(l2 - mx);
  float inv = 1.0f / (e0 + e1 + e2);
  o0 = e0 * inv; o1 = e1 * inv; o2 = e2 * inv;
}

// nontemporal float4 store: out is write-once streaming; nt keeps it from
// evicting x (134 MB) out of the 256 MB Infinity Cache between K1 and K2 reads.
DEV_INLINE void nt_store(float4* p, float4 v) {
  f4v t; t.x = v.x; t.y = v.y; t.z = v.z; t.w = v.w;
  __builtin_nontemporal_store(t, reinterpret_cast<f4v*>(p));
}

// ---------------- K1: fused prep + per-chunk local suffix ----------------
__global__ __launch_bounds__(128) void ema_k1(const float* __restrict__ x,
                                              const float* __restrict__ logit_alpha,
                                              float* __restrict__ carry_f) {
  const int c4 = threadIdx.x;          // 0..C4-1
  const int bi = blockIdx.x;           // b*NC + chunk
  const int i  = bi & (NC - 1);

  // per-block recompute of a,b (~12 exps/thread, free vs. a table pass)
  const float4* la = (const float4*)logit_alpha;
  const float4 a0 = sig4(la[0 * C4 + c4]);
  const float4 a1 = sig4(la[1 * C4 + c4]);
  const float4 a2 = sig4(la[2 * C4 + c4]);
  const float4 b0 = f4onesub(a0), b1 = f4onesub(a1), b2 = f4onesub(a2);

  const float4* xb = (const float4*)x + (size_t)bi * L * C4 + c4;

  float4 y0, y1, y2;
  int jstart;
  if (i == 0) {
    // chunk 0: y[0] = x[0] exactly (no incoming state)
    float4 x0 = xb[0];
    y0 = x0; y1 = x0; y2 = x0;
    jstart = 1;
  } else {
    y0 = make_float4(0.f, 0.f, 0.f, 0.f);
    y1 = y0; y2 = y0;
    jstart = 0;
  }

  #pragma unroll 4
  for (int j = jstart; j < L; ++j) {
    float4 xv = xb[(size_t)j * C4];
    y0 = f4fma(a0, y0, f4mul(b0, xv));
    y1 = f4fma(a1, y1, f4mul(b1, xv));
    y2 = f4fma(a2, y2, f4mul(b2, xv));
  }

  float4* carry = (float4*)carry_f;
  const size_t cb = (size_t)bi * (K * C4) + c4;
  carry[cb + 0 * C4] = y0;
  carry[cb + 1 * C4] = y1;
  carry[cb + 2 * C4] = y2;
}

// ---------------- K2: inline carry-scan + recurrence + mix, streamed out ----------------
__global__ __launch_bounds__(128) void ema_k2(const float* __restrict__ x,
                                              const float* __restrict__ logit_alpha,
                                              const float* __restrict__ mix_logits,
                                              const float* __restrict__ carry_f,
                                              float* __restrict__ out) {
  const int c4 = threadIdx.x;
  const int bi = blockIdx.x;
  const int i  = bi & (NC - 1);
  const int b  = bi >> 6;              // NC = 64

  const float4* la = (const float4*)logit_alpha;
  const float4 a0 = sig4(la[0 * C4 + c4]);
  const float4 a1 = sig4(la[1 * C4 + c4]);
  const float4 a2 = sig4(la[2 * C4 + c4]);
  const float4 b0 = f4onesub(a0), b1 = f4onesub(a1), b2 = f4onesub(a2);

  // mix softmax: channels 4*c4 .. 4*c4+3; mix_logits is [C][K], 12 floats/thread
  const float4* ml = (const float4*)mix_logits;
  const float4 q0 = ml[3 * c4 + 0];
  const float4 q1 = ml[3 * c4 + 1];
  const float4 q2 = ml[3 * c4 + 2];
  float4 m0, m1, m2;
  sm3(q0.x, q0.y, q0.z, m0.x, m1.x, m2.x);
  sm3(q0.w, q1.x, q1.y, m0.y, m1.y, m2.y);
  sm3(q1.z, q1.w, q2.x, m0.z, m1.z, m2.z);
  sm3(q2.y, q2.z, q2.w, m0.w, m1.w, m2.w);

  const float4* xb = (const float4*)x + (size_t)bi * L * C4 + c4;
  float4*       ob = (float4*)out     + (size_t)bi * L * C4 + c4;

  float4 y0, y1, y2;
  int jstart;
  if (i == 0) {
    float4 x0 = xb[0];
    y0 = x0; y1 = x0; y2 = x0;
    nt_store(&ob[0], f4fma(m0, y0, f4fma(m1, y1, f4mul(m2, y2))));
    jstart = 1;
  } else {
    // A = a^L via 6 squarings (L = 64)
    float4 A0 = a0, A1 = a1, A2 = a2;
    #pragma unroll
    for (int s = 0; s < 6; ++s) { A0 = f4mul(A0, A0); A1 = f4mul(A1, A1); A2 = f4mul(A2, A2); }

    // incoming state for chunk i = E_{i-1}; E_0 = s_0, E_j = A*E_{j-1} + s_j
    const size_t stride = (size_t)K * C4;
    const float4* cb = (const float4*)carry_f + (size_t)b * NC * stride + c4;
    y0 = cb[0 * C4];
    y1 = cb[1 * C4];
    y2 = cb[2 * C4];
    #pragma unroll 4
    for (int j = 1; j < i; ++j) {
      const float4* cj = cb + (size_t)j * stride;
      y0 = f4fma(A0, y0, cj[0 * C4]);
      y1 = f4fma(A1, y1, cj[1 * C4]);
      y2 = f4fma(A2, y2, cj[2 * C4]);
    }
    jstart = 0;
  }

  #pragma unroll 4
  for (int j = jstart; j < L; ++j) {
    float4 xv = xb[(size_t)j * C4];     // L3-resident (K1 just streamed x through L3)
    y0 = f4fma(a0, y0, f4mul(b0, xv));
    y1 = f4fma(a1, y1, f4mul(b1, xv));
    y2 = f4fma(a2, y2, f4mul(b2, xv));
    nt_store(&ob[(size_t)j * C4], f4fma(m0, y0, f4fma(m1, y1, f4mul(m2, y2))));
  }
}

extern "C" void kernel_launch(void* const* d_in, const int* in_sizes, int n_in,
                              void* d_out, int out_size, void* d_ws, size_t ws_size,
                              hipStream_t stream) {
  const float* x           = (const float*)d_in[0];
  const float* logit_alpha = (const float*)d_in[1];
  const float* mix_logits  = (const float*)d_in[2];
  float* out = (float*)d_out;
  float* ws  = (float*)d_ws;

  ema_k1<<<B * NC, 128, 0, stream>>>(x, logit_alpha, ws);
  ema_k2<<<B * NC, 128, 0, stream>>>(x, logit_alpha, mix_logits, ws, out);
}